// Round 2
// baseline (895.343 us; speedup 1.0000x reference)
//
#include <hip/hip_runtime.h>

#define DIM 64
#define NGRAPHS 128
#define BN_EPS 1e-5f

// ---------------------------------------------------------------------------
// CSR build (once per call): histogram -> exclusive scan -> scatter.
// ---------------------------------------------------------------------------
__global__ __launch_bounds__(256) void hist_kernel(
    const int* __restrict__ ei, int* __restrict__ deg, int E)
{
    int e = blockIdx.x * 256 + threadIdx.x;
    if (e < E) atomicAdd(&deg[ei[E + e]], 1);   // dst
}

// single block, 256 threads: exclusive scan of deg[N] -> rowptr[N+1], cursor[N]
__global__ __launch_bounds__(256) void scan_kernel(
    const int* __restrict__ deg, int* __restrict__ rowptr,
    int* __restrict__ cursor, int N)
{
    __shared__ int tsum[256];
    const int t = threadIdx.x;
    const int chunk = (N + 255) / 256;
    const int start = t * chunk;
    const int end   = min(start + chunk, N);
    int s = 0;
    for (int i = start; i < end; ++i) s += deg[i];
    tsum[t] = s;
    __syncthreads();
    if (t == 0) {
        int a = 0;
        for (int i = 0; i < 256; ++i) { int v = tsum[i]; tsum[i] = a; a += v; }
    }
    __syncthreads();
    int off = tsum[t];
    for (int i = start; i < end; ++i) {
        int v = deg[i];
        rowptr[i] = off; cursor[i] = off;
        off += v;
    }
    if (end == N && start <= N) rowptr[N] = off;   // last chunk writes total
}

__global__ __launch_bounds__(256) void scatter_kernel(
    const int* __restrict__ ei, int* __restrict__ cursor,
    int* __restrict__ col, int E)
{
    int e = blockIdx.x * 256 + threadIdx.x;
    if (e >= E) return;
    int d = ei[E + e];
    int p = atomicAdd(&cursor[d], 1);
    col[p] = ei[e];                                // src
}

// ---------------------------------------------------------------------------
// Aggregation by gather: 16 lanes per node, each owns 4 consecutive floats.
// Per neighbor: 16 lanes read one contiguous 256B row (coalesced). No atomics.
// ---------------------------------------------------------------------------
__global__ __launch_bounds__(256) void agg_gather(
    const float* __restrict__ h, const int* __restrict__ rowptr,
    const int* __restrict__ col, float* __restrict__ agg, int N)
{
    long idx = (long)blockIdx.x * 256 + threadIdx.x;
    int node = (int)(idx >> 4);
    int t = (int)(idx & 15);
    if (node >= N) return;
    const int lo = rowptr[node], hi = rowptr[node + 1];
    float4 acc = {0.f, 0.f, 0.f, 0.f};
    int e = lo;
    for (; e + 1 < hi; e += 2) {                   // 2-way unroll for MLP
        int s0 = col[e], s1 = col[e + 1];
        const float4 v0 = *reinterpret_cast<const float4*>(h + (long)s0 * DIM + t * 4);
        const float4 v1 = *reinterpret_cast<const float4*>(h + (long)s1 * DIM + t * 4);
        acc.x += v0.x; acc.y += v0.y; acc.z += v0.z; acc.w += v0.w;
        acc.x += v1.x; acc.y += v1.y; acc.z += v1.z; acc.w += v1.w;
    }
    if (e < hi) {
        int s0 = col[e];
        const float4 v0 = *reinterpret_cast<const float4*>(h + (long)s0 * DIM + t * 4);
        acc.x += v0.x; acc.y += v0.y; acc.z += v0.z; acc.w += v0.w;
    }
    *reinterpret_cast<float4*>(agg + (long)node * DIM + t * 4) = acc;
}

// ---------------------------------------------------------------------------
// Fused node update (unchanged):
//   z = hin[i] (+ agg[i]); y = relu(BN(z@W1+b1)); hout = (relu?)(y@W2+b2)
// BN folded into W1 columns + bias at LDS-load time.
// ---------------------------------------------------------------------------
template<bool HAS_AGG, bool BN, bool RELU2>
__global__ __launch_bounds__(256) void node_update(
    const float* __restrict__ hin, const float* __restrict__ agg,
    const float* __restrict__ W1, const float* __restrict__ b1,
    const float* __restrict__ gamma, const float* __restrict__ beta,
    const float* __restrict__ rmean, const float* __restrict__ rvar,
    const float* __restrict__ W2, const float* __restrict__ b2,
    float* __restrict__ hout, int N)
{
    __shared__ float w1[DIM * DIM];
    __shared__ float w2[DIM * DIM];
    __shared__ float bb1[DIM];
    __shared__ float bb2[DIM];
    __shared__ float sc[DIM];

    const int tid = threadIdx.x;

    if (tid < DIM) {
        float s = 1.0f;
        float t0 = b1[tid];
        if constexpr (BN) {
            s = gamma[tid] * rsqrtf(rvar[tid] + BN_EPS);
            t0 = (b1[tid] - rmean[tid]) * s + beta[tid];
        }
        sc[tid]  = s;
        bb1[tid] = t0;
        bb2[tid] = b2[tid];
    }
    __syncthreads();

    for (int f = tid * 4; f < DIM * DIM; f += 256 * 4) {
        float4 a = *reinterpret_cast<const float4*>(W1 + f);
        int j = f & (DIM - 1);
        a.x *= sc[j]; a.y *= sc[j + 1]; a.z *= sc[j + 2]; a.w *= sc[j + 3];
        *reinterpret_cast<float4*>(w1 + f) = a;
        float4 c = *reinterpret_cast<const float4*>(W2 + f);
        *reinterpret_cast<float4*>(w2 + f) = c;
    }
    __syncthreads();

    const int i = blockIdx.x * 256 + tid;
    if (i >= N) return;

    float z[DIM];
    const float4* hr = reinterpret_cast<const float4*>(hin + (long)i * DIM);
#pragma unroll
    for (int k = 0; k < DIM / 4; ++k) {
        float4 a = hr[k];
        z[4 * k] = a.x; z[4 * k + 1] = a.y; z[4 * k + 2] = a.z; z[4 * k + 3] = a.w;
    }
    if constexpr (HAS_AGG) {
        const float4* ar = reinterpret_cast<const float4*>(agg + (long)i * DIM);
#pragma unroll
        for (int k = 0; k < DIM / 4; ++k) {
            float4 a = ar[k];
            z[4 * k] += a.x; z[4 * k + 1] += a.y; z[4 * k + 2] += a.z; z[4 * k + 3] += a.w;
        }
    }

    float acc[DIM];
#pragma unroll
    for (int j = 0; j < DIM; ++j) acc[j] = bb1[j];
#pragma unroll
    for (int k = 0; k < DIM; ++k) {
        const float zk = z[k];
#pragma unroll
        for (int j = 0; j < DIM / 4; ++j) {
            float4 w = *reinterpret_cast<const float4*>(w1 + k * DIM + 4 * j);
            acc[4 * j]     = fmaf(zk, w.x, acc[4 * j]);
            acc[4 * j + 1] = fmaf(zk, w.y, acc[4 * j + 1]);
            acc[4 * j + 2] = fmaf(zk, w.z, acc[4 * j + 2]);
            acc[4 * j + 3] = fmaf(zk, w.w, acc[4 * j + 3]);
        }
    }
#pragma unroll
    for (int j = 0; j < DIM; ++j) z[j] = fmaxf(acc[j], 0.0f);

#pragma unroll
    for (int j = 0; j < DIM; ++j) acc[j] = bb2[j];
#pragma unroll
    for (int k = 0; k < DIM; ++k) {
        const float zk = z[k];
#pragma unroll
        for (int j = 0; j < DIM / 4; ++j) {
            float4 w = *reinterpret_cast<const float4*>(w2 + k * DIM + 4 * j);
            acc[4 * j]     = fmaf(zk, w.x, acc[4 * j]);
            acc[4 * j + 1] = fmaf(zk, w.y, acc[4 * j + 1]);
            acc[4 * j + 2] = fmaf(zk, w.z, acc[4 * j + 2]);
            acc[4 * j + 3] = fmaf(zk, w.w, acc[4 * j + 3]);
        }
    }

    float4* outr = reinterpret_cast<float4*>(hout + (long)i * DIM);
#pragma unroll
    for (int j = 0; j < DIM / 4; ++j) {
        float4 o;
        o.x = acc[4 * j]; o.y = acc[4 * j + 1]; o.z = acc[4 * j + 2]; o.w = acc[4 * j + 3];
        if constexpr (RELU2) {
            o.x = fmaxf(o.x, 0.f); o.y = fmaxf(o.y, 0.f);
            o.z = fmaxf(o.z, 0.f); o.w = fmaxf(o.w, 0.f);
        }
        outr[j] = o;
    }
}

// ---------------------------------------------------------------------------
// Global add-pool: batch_ids sorted -> block g binary-searches its range.
// ---------------------------------------------------------------------------
__global__ __launch_bounds__(256) void pool_kernel(
    const float* __restrict__ h, const int* __restrict__ bid,
    float* __restrict__ out, int N)
{
    const int g = blockIdx.x;
    int lo, hi;
    { int a = 0, b = N; while (a < b) { int m = (a + b) >> 1; if (bid[m] < g) a = m + 1; else b = m; } lo = a; }
    { int a = lo, b = N; while (a < b) { int m = (a + b) >> 1; if (bid[m] < g + 1) a = m + 1; else b = m; } hi = a; }

    const int f  = threadIdx.x & 63;
    const int nl = threadIdx.x >> 6;
    float sum = 0.0f;
    for (int i = lo + nl; i < hi; i += 4)
        sum += h[(long)i * DIM + f];

    __shared__ float red[256];
    red[threadIdx.x] = sum;
    __syncthreads();
    if (threadIdx.x < 64)
        out[g * DIM + f] = red[f] + red[64 + f] + red[128 + f] + red[192 + f];
}

// ---------------------------------------------------------------------------
extern "C" void kernel_launch(void* const* d_in, const int* in_sizes, int n_in,
                              void* d_out, int out_size, void* d_ws, size_t ws_size,
                              hipStream_t stream)
{
    const float* x     = (const float*)d_in[0];
    const int*   ei    = (const int*)d_in[1];
    const int*   bid   = (const int*)d_in[2];
    const float* W1    = (const float*)d_in[3];
    const float* b1    = (const float*)d_in[4];
    const float* gamma = (const float*)d_in[5];
    const float* beta  = (const float*)d_in[6];
    const float* rmean = (const float*)d_in[7];
    const float* rvar  = (const float*)d_in[8];
    const float* W2    = (const float*)d_in[9];
    const float* b2    = (const float*)d_in[10];
    const float* Wm1   = (const float*)d_in[11];
    const float* bm1   = (const float*)d_in[12];
    const float* Wm2   = (const float*)d_in[13];
    const float* bm2   = (const float*)d_in[14];

    const int N = in_sizes[0] / DIM;
    const int E = in_sizes[1] / 2;
    const int L = in_sizes[3] / (DIM * DIM);

    // workspace layout (16B-aligned floats first, then ints)
    float* h      = (float*)d_ws;                        // N*64 f32
    float* agg    = h + (size_t)N * DIM;                 // N*64 f32
    int*   rowptr = (int*)(agg + (size_t)N * DIM);       // N+1
    int*   deg    = rowptr + (N + 1);                    // N
    int*   cursor = deg + N;                             // N
    int*   col    = cursor + N;                          // E
    float* out    = (float*)d_out;

    const int blkE = (E + 255) / 256;
    const int blkB = (N + 255) / 256;
    const int blkG = (int)(((long)N * 16 + 255) / 256);

    // ---- CSR build (once per call)
    hipMemsetAsync(deg, 0, (size_t)N * sizeof(int), stream);
    hist_kernel<<<blkE, 256, 0, stream>>>(ei, deg, E);
    scan_kernel<<<1, 256, 0, stream>>>(deg, rowptr, cursor, N);
    scatter_kernel<<<blkE, 256, 0, stream>>>(ei, cursor, col, E);

    // ---- GIN layers
    for (int l = 0; l < L; ++l) {
        const float* hin = (l == 0) ? x : h;
        agg_gather<<<blkG, 256, 0, stream>>>(hin, rowptr, col, agg, N);
        node_update<true, true, true><<<blkB, 256, 0, stream>>>(
            hin, agg,
            W1 + (size_t)l * DIM * DIM, b1 + (size_t)l * DIM,
            gamma + (size_t)l * DIM, beta + (size_t)l * DIM,
            rmean + (size_t)l * DIM, rvar + (size_t)l * DIM,
            W2 + (size_t)l * DIM * DIM, b2 + (size_t)l * DIM,
            h, N);
    }
    // ---- MLP (no BN, no final relu)
    node_update<false, false, false><<<blkB, 256, 0, stream>>>(
        h, nullptr, Wm1, bm1, nullptr, nullptr, nullptr, nullptr,
        Wm2, bm2, h, N);
    // ---- pool
    pool_kernel<<<NGRAPHS, 256, 0, stream>>>(h, bid, out, N);
}

// Round 3
// 880.596 us; speedup vs baseline: 1.0167x; 1.0167x over previous
//
#include <hip/hip_runtime.h>

#define DIM 64
#define NGRAPHS 128
#define BN_EPS 1e-5f
#define SCAN_BLK 2048   // 256 threads x 8 elements

// ---------------------------------------------------------------------------
// CSR build (once per call): histogram -> 3-phase parallel scan -> scatter.
// ---------------------------------------------------------------------------
__global__ __launch_bounds__(256) void hist_kernel(
    const int* __restrict__ ei, int* __restrict__ deg, int E)
{
    int e = blockIdx.x * 256 + threadIdx.x;
    if (e < E) atomicAdd(&deg[ei[E + e]], 1);   // dst
}

// Phase 1: per-block sums of deg (2048 elements/block)
__global__ __launch_bounds__(256) void scan_part(
    const int* __restrict__ deg, int* __restrict__ bsum, int N)
{
    const int base = blockIdx.x * SCAN_BLK + threadIdx.x * 8;
    int s = 0;
    if (base + 8 <= N) {
        int4 a = *reinterpret_cast<const int4*>(deg + base);
        int4 b = *reinterpret_cast<const int4*>(deg + base + 4);
        s = a.x + a.y + a.z + a.w + b.x + b.y + b.z + b.w;
    } else {
        for (int i = base; i < N && i < base + 8; ++i) s += deg[i];
    }
    for (int d = 32; d > 0; d >>= 1) s += __shfl_down(s, d);
    __shared__ int wsum[4];
    const int wave = threadIdx.x >> 6, lane = threadIdx.x & 63;
    if (lane == 0) wsum[wave] = s;
    __syncthreads();
    if (threadIdx.x == 0) bsum[blockIdx.x] = wsum[0] + wsum[1] + wsum[2] + wsum[3];
}

// Phase 2: exclusive scan of block sums (nb ~ 40) in-place; bsum[nb] = total
__global__ void scan_top(int* __restrict__ bsum, int nb)
{
    if (threadIdx.x == 0) {
        int a = 0;
        for (int i = 0; i < nb; ++i) { int v = bsum[i]; bsum[i] = a; a += v; }
        bsum[nb] = a;
    }
}

// Phase 3: per-block exclusive scan + block offset -> rowptr, cursor
__global__ __launch_bounds__(256) void scan_final(
    const int* __restrict__ deg, const int* __restrict__ bsum,
    int* __restrict__ rowptr, int* __restrict__ cursor, int N, int nb)
{
    const int t = threadIdx.x;
    const int base = blockIdx.x * SCAN_BLK + t * 8;
    int v[8];
    int s = 0;
#pragma unroll
    for (int k = 0; k < 8; ++k) {
        int i = base + k;
        int d = (i < N) ? deg[i] : 0;
        v[k] = s; s += d;                      // local exclusive prefix
    }
    const int lane = t & 63, wave = t >> 6;
    int inc = s;
    for (int d = 1; d < 64; d <<= 1) {         // wave inclusive scan
        int up = __shfl_up(inc, d);
        if (lane >= d) inc += up;
    }
    __shared__ int wtot[4];
    if (lane == 63) wtot[wave] = inc;
    __syncthreads();
    int woff = 0;
    for (int w = 0; w < wave; ++w) woff += wtot[w];
    const int texcl = (inc - s) + woff + bsum[blockIdx.x];
#pragma unroll
    for (int k = 0; k < 8; ++k) {
        int i = base + k;
        if (i < N) { int r = texcl + v[k]; rowptr[i] = r; cursor[i] = r; }
    }
    if (blockIdx.x == 0 && t == 0) rowptr[N] = bsum[nb];
}

__global__ __launch_bounds__(256) void scatter_kernel(
    const int* __restrict__ ei, int* __restrict__ cursor,
    int* __restrict__ col, int E)
{
    int e = blockIdx.x * 256 + threadIdx.x;
    if (e >= E) return;
    int d = ei[E + e];
    int p = atomicAdd(&cursor[d], 1);
    col[p] = ei[e];                            // src
}

// ---------------------------------------------------------------------------
// Aggregation by gather: 16 lanes per node, each owns 4 consecutive floats.
// Per neighbor: 16 lanes read one contiguous 256B row (coalesced). No atomics.
// ---------------------------------------------------------------------------
__global__ __launch_bounds__(256) void agg_gather(
    const float* __restrict__ h, const int* __restrict__ rowptr,
    const int* __restrict__ col, float* __restrict__ agg, int N)
{
    long idx = (long)blockIdx.x * 256 + threadIdx.x;
    int node = (int)(idx >> 4);
    int t = (int)(idx & 15);
    if (node >= N) return;
    const int lo = rowptr[node], hi = rowptr[node + 1];
    float4 acc = {0.f, 0.f, 0.f, 0.f};
    int e = lo;
    for (; e + 1 < hi; e += 2) {
        int s0 = col[e], s1 = col[e + 1];
        const float4 v0 = *reinterpret_cast<const float4*>(h + (long)s0 * DIM + t * 4);
        const float4 v1 = *reinterpret_cast<const float4*>(h + (long)s1 * DIM + t * 4);
        acc.x += v0.x; acc.y += v0.y; acc.z += v0.z; acc.w += v0.w;
        acc.x += v1.x; acc.y += v1.y; acc.z += v1.z; acc.w += v1.w;
    }
    if (e < hi) {
        int s0 = col[e];
        const float4 v0 = *reinterpret_cast<const float4*>(h + (long)s0 * DIM + t * 4);
        acc.x += v0.x; acc.y += v0.y; acc.z += v0.z; acc.w += v0.w;
    }
    *reinterpret_cast<float4*>(agg + (long)node * DIM + t * 4) = acc;
}

// ---------------------------------------------------------------------------
// Fused node update:
//   z = hin[i] (+ agg[i]); y = relu(BN(z@W1+b1)); hout = (relu?)(y@W2+b2)
// BN folded into W1 columns + bias at LDS-load time.
// ---------------------------------------------------------------------------
template<bool HAS_AGG, bool BN, bool RELU2>
__global__ __launch_bounds__(256) void node_update(
    const float* __restrict__ hin, const float* __restrict__ agg,
    const float* __restrict__ W1, const float* __restrict__ b1,
    const float* __restrict__ gamma, const float* __restrict__ beta,
    const float* __restrict__ rmean, const float* __restrict__ rvar,
    const float* __restrict__ W2, const float* __restrict__ b2,
    float* __restrict__ hout, int N)
{
    __shared__ float w1[DIM * DIM];
    __shared__ float w2[DIM * DIM];
    __shared__ float bb1[DIM];
    __shared__ float bb2[DIM];
    __shared__ float sc[DIM];

    const int tid = threadIdx.x;

    if (tid < DIM) {
        float s = 1.0f;
        float t0 = b1[tid];
        if constexpr (BN) {
            s = gamma[tid] * rsqrtf(rvar[tid] + BN_EPS);
            t0 = (b1[tid] - rmean[tid]) * s + beta[tid];
        }
        sc[tid]  = s;
        bb1[tid] = t0;
        bb2[tid] = b2[tid];
    }
    __syncthreads();

    for (int f = tid * 4; f < DIM * DIM; f += 256 * 4) {
        float4 a = *reinterpret_cast<const float4*>(W1 + f);
        int j = f & (DIM - 1);
        a.x *= sc[j]; a.y *= sc[j + 1]; a.z *= sc[j + 2]; a.w *= sc[j + 3];
        *reinterpret_cast<float4*>(w1 + f) = a;
        float4 c = *reinterpret_cast<const float4*>(W2 + f);
        *reinterpret_cast<float4*>(w2 + f) = c;
    }
    __syncthreads();

    const int i = blockIdx.x * 256 + tid;
    if (i >= N) return;

    float z[DIM];
    const float4* hr = reinterpret_cast<const float4*>(hin + (long)i * DIM);
#pragma unroll
    for (int k = 0; k < DIM / 4; ++k) {
        float4 a = hr[k];
        z[4 * k] = a.x; z[4 * k + 1] = a.y; z[4 * k + 2] = a.z; z[4 * k + 3] = a.w;
    }
    if constexpr (HAS_AGG) {
        const float4* ar = reinterpret_cast<const float4*>(agg + (long)i * DIM);
#pragma unroll
        for (int k = 0; k < DIM / 4; ++k) {
            float4 a = ar[k];
            z[4 * k] += a.x; z[4 * k + 1] += a.y; z[4 * k + 2] += a.z; z[4 * k + 3] += a.w;
        }
    }

    float acc[DIM];
#pragma unroll
    for (int j = 0; j < DIM; ++j) acc[j] = bb1[j];
#pragma unroll
    for (int k = 0; k < DIM; ++k) {
        const float zk = z[k];
#pragma unroll
        for (int j = 0; j < DIM / 4; ++j) {
            float4 w = *reinterpret_cast<const float4*>(w1 + k * DIM + 4 * j);
            acc[4 * j]     = fmaf(zk, w.x, acc[4 * j]);
            acc[4 * j + 1] = fmaf(zk, w.y, acc[4 * j + 1]);
            acc[4 * j + 2] = fmaf(zk, w.z, acc[4 * j + 2]);
            acc[4 * j + 3] = fmaf(zk, w.w, acc[4 * j + 3]);
        }
    }
#pragma unroll
    for (int j = 0; j < DIM; ++j) z[j] = fmaxf(acc[j], 0.0f);

#pragma unroll
    for (int j = 0; j < DIM; ++j) acc[j] = bb2[j];
#pragma unroll
    for (int k = 0; k < DIM; ++k) {
        const float zk = z[k];
#pragma unroll
        for (int j = 0; j < DIM / 4; ++j) {
            float4 w = *reinterpret_cast<const float4*>(w2 + k * DIM + 4 * j);
            acc[4 * j]     = fmaf(zk, w.x, acc[4 * j]);
            acc[4 * j + 1] = fmaf(zk, w.y, acc[4 * j + 1]);
            acc[4 * j + 2] = fmaf(zk, w.z, acc[4 * j + 2]);
            acc[4 * j + 3] = fmaf(zk, w.w, acc[4 * j + 3]);
        }
    }

    float4* outr = reinterpret_cast<float4*>(hout + (long)i * DIM);
#pragma unroll
    for (int j = 0; j < DIM / 4; ++j) {
        float4 o;
        o.x = acc[4 * j]; o.y = acc[4 * j + 1]; o.z = acc[4 * j + 2]; o.w = acc[4 * j + 3];
        if constexpr (RELU2) {
            o.x = fmaxf(o.x, 0.f); o.y = fmaxf(o.y, 0.f);
            o.z = fmaxf(o.z, 0.f); o.w = fmaxf(o.w, 0.f);
        }
        outr[j] = o;
    }
}

// ---------------------------------------------------------------------------
// Global add-pool: batch_ids sorted -> block g binary-searches its range.
// ---------------------------------------------------------------------------
__global__ __launch_bounds__(256) void pool_kernel(
    const float* __restrict__ h, const int* __restrict__ bid,
    float* __restrict__ out, int N)
{
    const int g = blockIdx.x;
    int lo, hi;
    { int a = 0, b = N; while (a < b) { int m = (a + b) >> 1; if (bid[m] < g) a = m + 1; else b = m; } lo = a; }
    { int a = lo, b = N; while (a < b) { int m = (a + b) >> 1; if (bid[m] < g + 1) a = m + 1; else b = m; } hi = a; }

    const int f  = threadIdx.x & 63;
    const int nl = threadIdx.x >> 6;
    float sum = 0.0f;
    for (int i = lo + nl; i < hi; i += 4)
        sum += h[(long)i * DIM + f];

    __shared__ float red[256];
    red[threadIdx.x] = sum;
    __syncthreads();
    if (threadIdx.x < 64)
        out[g * DIM + f] = red[f] + red[64 + f] + red[128 + f] + red[192 + f];
}

// ---------------------------------------------------------------------------
extern "C" void kernel_launch(void* const* d_in, const int* in_sizes, int n_in,
                              void* d_out, int out_size, void* d_ws, size_t ws_size,
                              hipStream_t stream)
{
    const float* x     = (const float*)d_in[0];
    const int*   ei    = (const int*)d_in[1];
    const int*   bid   = (const int*)d_in[2];
    const float* W1    = (const float*)d_in[3];
    const float* b1    = (const float*)d_in[4];
    const float* gamma = (const float*)d_in[5];
    const float* beta  = (const float*)d_in[6];
    const float* rmean = (const float*)d_in[7];
    const float* rvar  = (const float*)d_in[8];
    const float* W2    = (const float*)d_in[9];
    const float* b2    = (const float*)d_in[10];
    const float* Wm1   = (const float*)d_in[11];
    const float* bm1   = (const float*)d_in[12];
    const float* Wm2   = (const float*)d_in[13];
    const float* bm2   = (const float*)d_in[14];

    const int N = in_sizes[0] / DIM;
    const int E = in_sizes[1] / 2;
    const int L = in_sizes[3] / (DIM * DIM);

    // workspace layout
    float* h      = (float*)d_ws;                        // N*64 f32
    float* agg    = h + (size_t)N * DIM;                 // N*64 f32
    int*   rowptr = (int*)(agg + (size_t)N * DIM);       // N+1
    int*   deg    = rowptr + (N + 1);                    // N
    int*   cursor = deg + N;                             // N
    int*   col    = cursor + N;                          // E
    int*   bsum   = col + E;                             // nb+1
    float* out    = (float*)d_out;

    const int blkE = (E + 255) / 256;
    const int blkB = (N + 255) / 256;
    const int blkG = (int)(((long)N * 16 + 255) / 256);
    const int nb   = (N + SCAN_BLK - 1) / SCAN_BLK;

    // ---- CSR build (once per call)
    hipMemsetAsync(deg, 0, (size_t)N * sizeof(int), stream);
    hist_kernel<<<blkE, 256, 0, stream>>>(ei, deg, E);
    scan_part<<<nb, 256, 0, stream>>>(deg, bsum, N);
    scan_top<<<1, 64, 0, stream>>>(bsum, nb);
    scan_final<<<nb, 256, 0, stream>>>(deg, bsum, rowptr, cursor, N, nb);
    scatter_kernel<<<blkE, 256, 0, stream>>>(ei, cursor, col, E);

    // ---- GIN layers
    for (int l = 0; l < L; ++l) {
        const float* hin = (l == 0) ? x : h;
        agg_gather<<<blkG, 256, 0, stream>>>(hin, rowptr, col, agg, N);
        node_update<true, true, true><<<blkB, 256, 0, stream>>>(
            hin, agg,
            W1 + (size_t)l * DIM * DIM, b1 + (size_t)l * DIM,
            gamma + (size_t)l * DIM, beta + (size_t)l * DIM,
            rmean + (size_t)l * DIM, rvar + (size_t)l * DIM,
            W2 + (size_t)l * DIM * DIM, b2 + (size_t)l * DIM,
            h, N);
    }
    // ---- MLP (no BN, no final relu)
    node_update<false, false, false><<<blkB, 256, 0, stream>>>(
        h, nullptr, Wm1, bm1, nullptr, nullptr, nullptr, nullptr,
        Wm2, bm2, h, N);
    // ---- pool
    pool_kernel<<<NGRAPHS, 256, 0, stream>>>(h, bid, out, N);
}

// Round 4
// 634.791 us; speedup vs baseline: 1.4105x; 1.3872x over previous
//
#include <hip/hip_runtime.h>

#define DIM 64
#define NGRAPHS 128
#define BN_EPS 1e-5f
#define SCAN_BLK 2048   // 256 threads x 8 elements

// ---------------------------------------------------------------------------
// CSR build (once per call): histogram -> 3-phase parallel scan -> scatter.
// ---------------------------------------------------------------------------
__global__ __launch_bounds__(256) void hist_kernel(
    const int* __restrict__ ei, int* __restrict__ deg, int E)
{
    int e = blockIdx.x * 256 + threadIdx.x;
    if (e < E) atomicAdd(&deg[ei[E + e]], 1);   // dst
}

__global__ __launch_bounds__(256) void scan_part(
    const int* __restrict__ deg, int* __restrict__ bsum, int N)
{
    const int base = blockIdx.x * SCAN_BLK + threadIdx.x * 8;
    int s = 0;
    if (base + 8 <= N) {
        int4 a = *reinterpret_cast<const int4*>(deg + base);
        int4 b = *reinterpret_cast<const int4*>(deg + base + 4);
        s = a.x + a.y + a.z + a.w + b.x + b.y + b.z + b.w;
    } else {
        for (int i = base; i < N && i < base + 8; ++i) s += deg[i];
    }
    for (int d = 32; d > 0; d >>= 1) s += __shfl_down(s, d);
    __shared__ int wsum[4];
    const int wave = threadIdx.x >> 6, lane = threadIdx.x & 63;
    if (lane == 0) wsum[wave] = s;
    __syncthreads();
    if (threadIdx.x == 0) bsum[blockIdx.x] = wsum[0] + wsum[1] + wsum[2] + wsum[3];
}

__global__ void scan_top(int* __restrict__ bsum, int nb)
{
    if (threadIdx.x == 0) {
        int a = 0;
        for (int i = 0; i < nb; ++i) { int v = bsum[i]; bsum[i] = a; a += v; }
        bsum[nb] = a;
    }
}

__global__ __launch_bounds__(256) void scan_final(
    const int* __restrict__ deg, const int* __restrict__ bsum,
    int* __restrict__ rowptr, int* __restrict__ cursor, int N, int nb)
{
    const int t = threadIdx.x;
    const int base = blockIdx.x * SCAN_BLK + t * 8;
    int v[8];
    int s = 0;
#pragma unroll
    for (int k = 0; k < 8; ++k) {
        int i = base + k;
        int d = (i < N) ? deg[i] : 0;
        v[k] = s; s += d;
    }
    const int lane = t & 63, wave = t >> 6;
    int inc = s;
    for (int d = 1; d < 64; d <<= 1) {
        int up = __shfl_up(inc, d);
        if (lane >= d) inc += up;
    }
    __shared__ int wtot[4];
    if (lane == 63) wtot[wave] = inc;
    __syncthreads();
    int woff = 0;
    for (int w = 0; w < wave; ++w) woff += wtot[w];
    const int texcl = (inc - s) + woff + bsum[blockIdx.x];
#pragma unroll
    for (int k = 0; k < 8; ++k) {
        int i = base + k;
        if (i < N) { int r = texcl + v[k]; rowptr[i] = r; cursor[i] = r; }
    }
    if (blockIdx.x == 0 && t == 0) rowptr[N] = bsum[nb];
}

__global__ __launch_bounds__(256) void scatter_kernel(
    const int* __restrict__ ei, int* __restrict__ cursor,
    int* __restrict__ col, int E)
{
    int e = blockIdx.x * 256 + threadIdx.x;
    if (e >= E) return;
    int d = ei[E + e];
    int p = atomicAdd(&cursor[d], 1);
    col[p] = ei[e];
}

// ---------------------------------------------------------------------------
// Aggregation by gather (unchanged this round for clean attribution).
// ---------------------------------------------------------------------------
__global__ __launch_bounds__(256) void agg_gather(
    const float* __restrict__ h, const int* __restrict__ rowptr,
    const int* __restrict__ col, float* __restrict__ agg, int N)
{
    long idx = (long)blockIdx.x * 256 + threadIdx.x;
    int node = (int)(idx >> 4);
    int t = (int)(idx & 15);
    if (node >= N) return;
    const int lo = rowptr[node], hi = rowptr[node + 1];
    float4 acc = {0.f, 0.f, 0.f, 0.f};
    int e = lo;
    for (; e + 1 < hi; e += 2) {
        int s0 = col[e], s1 = col[e + 1];
        const float4 v0 = *reinterpret_cast<const float4*>(h + (long)s0 * DIM + t * 4);
        const float4 v1 = *reinterpret_cast<const float4*>(h + (long)s1 * DIM + t * 4);
        acc.x += v0.x; acc.y += v0.y; acc.z += v0.z; acc.w += v0.w;
        acc.x += v1.x; acc.y += v1.y; acc.z += v1.z; acc.w += v1.w;
    }
    if (e < hi) {
        int s0 = col[e];
        const float4 v0 = *reinterpret_cast<const float4*>(h + (long)s0 * DIM + t * 4);
        acc.x += v0.x; acc.y += v0.y; acc.z += v0.z; acc.w += v0.w;
    }
    *reinterpret_cast<float4*>(agg + (long)node * DIM + t * 4) = acc;
}

// ---------------------------------------------------------------------------
// Fused node update, spill-free:
//   GEMV1 streams z (hin+agg) in float4 chunks into acc[64]  (64+8 live regs)
//   ReLU in place; GEMV2 computes 16 outputs at a time (a2[16]) re-sweeping
//   acc[64] with static indices.                              (~90 live regs)
// BN folded into W1 columns + bias at LDS-load time.
// ---------------------------------------------------------------------------
template<bool HAS_AGG, bool BN, bool RELU2>
__global__ __launch_bounds__(256) void node_update(
    const float* __restrict__ hin, const float* __restrict__ agg,
    const float* __restrict__ W1, const float* __restrict__ b1,
    const float* __restrict__ gamma, const float* __restrict__ beta,
    const float* __restrict__ rmean, const float* __restrict__ rvar,
    const float* __restrict__ W2, const float* __restrict__ b2,
    float* __restrict__ hout, int N)
{
    __shared__ float w1[DIM * DIM];
    __shared__ float w2[DIM * DIM];
    __shared__ float bb1[DIM];
    __shared__ float bb2[DIM];
    __shared__ float sc[DIM];

    const int tid = threadIdx.x;

    if (tid < DIM) {
        float s = 1.0f;
        float t0 = b1[tid];
        if constexpr (BN) {
            s = gamma[tid] * rsqrtf(rvar[tid] + BN_EPS);
            t0 = (b1[tid] - rmean[tid]) * s + beta[tid];
        }
        sc[tid]  = s;
        bb1[tid] = t0;
        bb2[tid] = b2[tid];
    }
    __syncthreads();

    for (int f = tid * 4; f < DIM * DIM; f += 256 * 4) {
        float4 a = *reinterpret_cast<const float4*>(W1 + f);
        int j = f & (DIM - 1);
        a.x *= sc[j]; a.y *= sc[j + 1]; a.z *= sc[j + 2]; a.w *= sc[j + 3];
        *reinterpret_cast<float4*>(w1 + f) = a;
        float4 c = *reinterpret_cast<const float4*>(W2 + f);
        *reinterpret_cast<float4*>(w2 + f) = c;
    }
    __syncthreads();

    const int i = blockIdx.x * 256 + tid;
    if (i >= N) return;

    // ---- GEMV1: acc = bb1 + z @ w1, z streamed in float4 chunks
    float acc[DIM];
#pragma unroll
    for (int j = 0; j < DIM; ++j) acc[j] = bb1[j];

    const float4* hr = reinterpret_cast<const float4*>(hin + (long)i * DIM);
    const float4* ar = reinterpret_cast<const float4*>(agg + (long)i * DIM);
#pragma unroll
    for (int kc = 0; kc < DIM / 4; ++kc) {
        float4 a = hr[kc];
        if constexpr (HAS_AGG) {
            float4 g = ar[kc];
            a.x += g.x; a.y += g.y; a.z += g.z; a.w += g.w;
        }
        float zs[4] = {a.x, a.y, a.z, a.w};
#pragma unroll
        for (int kk = 0; kk < 4; ++kk) {
            const float zk = zs[kk];
            const int k = kc * 4 + kk;
#pragma unroll
            for (int j = 0; j < DIM / 4; ++j) {
                float4 w = *reinterpret_cast<const float4*>(w1 + k * DIM + 4 * j);
                acc[4 * j]     = fmaf(zk, w.x, acc[4 * j]);
                acc[4 * j + 1] = fmaf(zk, w.y, acc[4 * j + 1]);
                acc[4 * j + 2] = fmaf(zk, w.z, acc[4 * j + 2]);
                acc[4 * j + 3] = fmaf(zk, w.w, acc[4 * j + 3]);
            }
        }
    }
    // y = relu(acc), in place
#pragma unroll
    for (int j = 0; j < DIM; ++j) acc[j] = fmaxf(acc[j], 0.0f);

    // ---- GEMV2: out = bb2 + acc @ w2, 16 outputs at a time
    float4* outr = reinterpret_cast<float4*>(hout + (long)i * DIM);
#pragma unroll
    for (int jc = 0; jc < 4; ++jc) {
        float a2[16];
#pragma unroll
        for (int jj = 0; jj < 16; ++jj) a2[jj] = bb2[jc * 16 + jj];
#pragma unroll
        for (int k = 0; k < DIM; ++k) {
            const float yk = acc[k];
#pragma unroll
            for (int q = 0; q < 4; ++q) {
                float4 w = *reinterpret_cast<const float4*>(w2 + k * DIM + jc * 16 + 4 * q);
                a2[4 * q]     = fmaf(yk, w.x, a2[4 * q]);
                a2[4 * q + 1] = fmaf(yk, w.y, a2[4 * q + 1]);
                a2[4 * q + 2] = fmaf(yk, w.z, a2[4 * q + 2]);
                a2[4 * q + 3] = fmaf(yk, w.w, a2[4 * q + 3]);
            }
        }
#pragma unroll
        for (int q = 0; q < 4; ++q) {
            float4 o = {a2[4 * q], a2[4 * q + 1], a2[4 * q + 2], a2[4 * q + 3]};
            if constexpr (RELU2) {
                o.x = fmaxf(o.x, 0.f); o.y = fmaxf(o.y, 0.f);
                o.z = fmaxf(o.z, 0.f); o.w = fmaxf(o.w, 0.f);
            }
            outr[jc * 4 + q] = o;
        }
    }
}

// ---------------------------------------------------------------------------
// Global add-pool: batch_ids sorted -> block g binary-searches its range.
// ---------------------------------------------------------------------------
__global__ __launch_bounds__(256) void pool_kernel(
    const float* __restrict__ h, const int* __restrict__ bid,
    float* __restrict__ out, int N)
{
    const int g = blockIdx.x;
    int lo, hi;
    { int a = 0, b = N; while (a < b) { int m = (a + b) >> 1; if (bid[m] < g) a = m + 1; else b = m; } lo = a; }
    { int a = lo, b = N; while (a < b) { int m = (a + b) >> 1; if (bid[m] < g + 1) a = m + 1; else b = m; } hi = a; }

    const int f  = threadIdx.x & 63;
    const int nl = threadIdx.x >> 6;
    float sum = 0.0f;
    for (int i = lo + nl; i < hi; i += 4)
        sum += h[(long)i * DIM + f];

    __shared__ float red[256];
    red[threadIdx.x] = sum;
    __syncthreads();
    if (threadIdx.x < 64)
        out[g * DIM + f] = red[f] + red[64 + f] + red[128 + f] + red[192 + f];
}

// ---------------------------------------------------------------------------
extern "C" void kernel_launch(void* const* d_in, const int* in_sizes, int n_in,
                              void* d_out, int out_size, void* d_ws, size_t ws_size,
                              hipStream_t stream)
{
    const float* x     = (const float*)d_in[0];
    const int*   ei    = (const int*)d_in[1];
    const int*   bid   = (const int*)d_in[2];
    const float* W1    = (const float*)d_in[3];
    const float* b1    = (const float*)d_in[4];
    const float* gamma = (const float*)d_in[5];
    const float* beta  = (const float*)d_in[6];
    const float* rmean = (const float*)d_in[7];
    const float* rvar  = (const float*)d_in[8];
    const float* W2    = (const float*)d_in[9];
    const float* b2    = (const float*)d_in[10];
    const float* Wm1   = (const float*)d_in[11];
    const float* bm1   = (const float*)d_in[12];
    const float* Wm2   = (const float*)d_in[13];
    const float* bm2   = (const float*)d_in[14];

    const int N = in_sizes[0] / DIM;
    const int E = in_sizes[1] / 2;
    const int L = in_sizes[3] / (DIM * DIM);

    float* h      = (float*)d_ws;                        // N*64 f32
    float* agg    = h + (size_t)N * DIM;                 // N*64 f32
    int*   rowptr = (int*)(agg + (size_t)N * DIM);       // N+1
    int*   deg    = rowptr + (N + 1);                    // N
    int*   cursor = deg + N;                             // N
    int*   col    = cursor + N;                          // E
    int*   bsum   = col + E;                             // nb+1
    float* out    = (float*)d_out;

    const int blkE = (E + 255) / 256;
    const int blkB = (N + 255) / 256;
    const int blkG = (int)(((long)N * 16 + 255) / 256);
    const int nb   = (N + SCAN_BLK - 1) / SCAN_BLK;

    // ---- CSR build (once per call)
    hipMemsetAsync(deg, 0, (size_t)N * sizeof(int), stream);
    hist_kernel<<<blkE, 256, 0, stream>>>(ei, deg, E);
    scan_part<<<nb, 256, 0, stream>>>(deg, bsum, N);
    scan_top<<<1, 64, 0, stream>>>(bsum, nb);
    scan_final<<<nb, 256, 0, stream>>>(deg, bsum, rowptr, cursor, N, nb);
    scatter_kernel<<<blkE, 256, 0, stream>>>(ei, cursor, col, E);

    // ---- GIN layers
    for (int l = 0; l < L; ++l) {
        const float* hin = (l == 0) ? x : h;
        agg_gather<<<blkG, 256, 0, stream>>>(hin, rowptr, col, agg, N);
        node_update<true, true, true><<<blkB, 256, 0, stream>>>(
            hin, agg,
            W1 + (size_t)l * DIM * DIM, b1 + (size_t)l * DIM,
            gamma + (size_t)l * DIM, beta + (size_t)l * DIM,
            rmean + (size_t)l * DIM, rvar + (size_t)l * DIM,
            W2 + (size_t)l * DIM * DIM, b2 + (size_t)l * DIM,
            h, N);
    }
    // ---- MLP (no BN, no final relu)
    node_update<false, false, false><<<blkB, 256, 0, stream>>>(
        h, nullptr, Wm1, bm1, nullptr, nullptr, nullptr, nullptr,
        Wm2, bm2, h, N);
    // ---- pool
    pool_kernel<<<NGRAPHS, 256, 0, stream>>>(h, bid, out, N);
}